// Round 16
// baseline (41.934 us; speedup 1.0000x reference)
//
#include <hip/hip_runtime.h>
#include <cmath>

#define B_ 4
#define N_ 512
#define F_ 128
#define BN_ (B_*N_)   // 2048
#define NG_ (BN_/4)   // 512 row-groups of 4

__device__ __forceinline__ float elu_f(float x) {
    return fmaxf(x, __expf(fminf(x, 0.f)) - 1.f);
}

// ---------------------------------------------------------------------------
// Kernel 1 (544 blocks x 512 thr):
//  blocks [0,512):   lin1 for 4 rows — Hi = H@dW1[:F]+db1, EHi = exp(Hi),
//                    HjT[b][f][n] = (H@dW1[F:])^T. K split across kq=t>>7.
//  blocks [512,544): colsum partials: csp[b][e][f] = sum of 64 H rows.
// ---------------------------------------------------------------------------
__global__ __launch_bounds__(512, 4) void k_pre(
    const float* __restrict__ H, const float* __restrict__ dW1,
    const float* __restrict__ db1,
    float* __restrict__ Hi, float* __restrict__ EHi, float* __restrict__ HjT,
    float* __restrict__ csp) {
    __shared__ float sH[4][F_];
    __shared__ float sPA[3][4][F_], sPB[3][4][F_];
    const int t = threadIdx.x;
    const int f = t & 127;
    const int kq = t >> 7;
    if (blockIdx.x < NG_) {
        // ---------------- lin1 ----------------
        const int row0 = blockIdx.x * 4;
        const int b  = row0 >> 9;
        const int n0 = row0 & 511;
        sH[kq][f] = H[(size_t)(row0 + kq) * F_ + f];
        __syncthreads();
        float accA[4] = {0.f,0.f,0.f,0.f}, accB[4] = {0.f,0.f,0.f,0.f};
        const int k0 = kq * 32;
        #pragma unroll 4
        for (int k = k0; k < k0 + 32; ++k) {
            const float wa = dW1[(size_t)k * F_ + f];
            const float wb = dW1[(size_t)(F_ + k) * F_ + f];
            #pragma unroll
            for (int r = 0; r < 4; ++r) {
                accA[r] = fmaf(sH[r][k], wa, accA[r]);
                accB[r] = fmaf(sH[r][k], wb, accB[r]);
            }
        }
        if (kq > 0) {
            #pragma unroll
            for (int r = 0; r < 4; ++r) {
                sPA[kq - 1][r][f] = accA[r];
                sPB[kq - 1][r][f] = accB[r];
            }
        }
        __syncthreads();
        if (kq == 0) {
            const float bias = db1[f];
            float bsum[4];
            #pragma unroll
            for (int r = 0; r < 4; ++r) {
                const float av = accA[r] + sPA[0][r][f] + sPA[1][r][f]
                               + sPA[2][r][f] + bias;
                Hi [(size_t)(row0 + r) * F_ + f] = av;
                EHi[(size_t)(row0 + r) * F_ + f] = __expf(av);
                bsum[r] = accB[r] + sPB[0][r][f] + sPB[1][r][f] + sPB[2][r][f];
            }
            float4 hv;
            hv.x = bsum[0]; hv.y = bsum[1]; hv.z = bsum[2]; hv.w = bsum[3];
            *reinterpret_cast<float4*>(HjT + ((size_t)b * F_ + f) * N_ + n0) = hv;
        }
    } else {
        // ---------------- colsum partial ----------------
        const int bx = blockIdx.x - NG_;   // 0..31
        const int b  = bx >> 3;
        const int e  = bx & 7;             // batch-eighth (64 rows)
        float s = 0.f;
        const float* hp = H + ((size_t)b * N_ + e * 64 + kq * 16) * F_ + f;
        #pragma unroll 4
        for (int jj = 0; jj < 16; ++jj) s += hp[(size_t)jj * F_];
        sH[kq][f] = s;
        __syncthreads();
        if (kq == 0)
            csp[((size_t)b * 8 + e) * F_ + f] =
                sH[0][f] + sH[1][f] + sH[2][f] + sH[3][f];
    }
}

// one f-slice: uniforms = component CP of (h0..h3, e0..e3, wq); 4 j's = HJ4.
#define SCORE_F(HJ4, CP) {                                                    \
    const float ejx = __expf((HJ4).x), ejy = __expf((HJ4).y),                 \
                ejz = __expf((HJ4).z), ejw = __expf((HJ4).w);                 \
    const float wv_ = wq.CP;                                                  \
    acc0.x = fmaf(__builtin_amdgcn_fmed3f(h0.CP + (HJ4).x, fmaf(e0.CP, ejx, -1.f), 0.f), wv_, acc0.x); \
    acc0.y = fmaf(__builtin_amdgcn_fmed3f(h0.CP + (HJ4).y, fmaf(e0.CP, ejy, -1.f), 0.f), wv_, acc0.y); \
    acc0.z = fmaf(__builtin_amdgcn_fmed3f(h0.CP + (HJ4).z, fmaf(e0.CP, ejz, -1.f), 0.f), wv_, acc0.z); \
    acc0.w = fmaf(__builtin_amdgcn_fmed3f(h0.CP + (HJ4).w, fmaf(e0.CP, ejw, -1.f), 0.f), wv_, acc0.w); \
    acc1.x = fmaf(__builtin_amdgcn_fmed3f(h1.CP + (HJ4).x, fmaf(e1.CP, ejx, -1.f), 0.f), wv_, acc1.x); \
    acc1.y = fmaf(__builtin_amdgcn_fmed3f(h1.CP + (HJ4).y, fmaf(e1.CP, ejy, -1.f), 0.f), wv_, acc1.y); \
    acc1.z = fmaf(__builtin_amdgcn_fmed3f(h1.CP + (HJ4).z, fmaf(e1.CP, ejz, -1.f), 0.f), wv_, acc1.z); \
    acc1.w = fmaf(__builtin_amdgcn_fmed3f(h1.CP + (HJ4).w, fmaf(e1.CP, ejw, -1.f), 0.f), wv_, acc1.w); \
    acc2.x = fmaf(__builtin_amdgcn_fmed3f(h2.CP + (HJ4).x, fmaf(e2.CP, ejx, -1.f), 0.f), wv_, acc2.x); \
    acc2.y = fmaf(__builtin_amdgcn_fmed3f(h2.CP + (HJ4).y, fmaf(e2.CP, ejy, -1.f), 0.f), wv_, acc2.y); \
    acc2.z = fmaf(__builtin_amdgcn_fmed3f(h2.CP + (HJ4).z, fmaf(e2.CP, ejz, -1.f), 0.f), wv_, acc2.z); \
    acc2.w = fmaf(__builtin_amdgcn_fmed3f(h2.CP + (HJ4).w, fmaf(e2.CP, ejw, -1.f), 0.f), wv_, acc2.w); \
    acc3.x = fmaf(__builtin_amdgcn_fmed3f(h3.CP + (HJ4).x, fmaf(e3.CP, ejx, -1.f), 0.f), wv_, acc3.x); \
    acc3.y = fmaf(__builtin_amdgcn_fmed3f(h3.CP + (HJ4).y, fmaf(e3.CP, ejy, -1.f), 0.f), wv_, acc3.y); \
    acc3.z = fmaf(__builtin_amdgcn_fmed3f(h3.CP + (HJ4).z, fmaf(e3.CP, ejz, -1.f), 0.f), wv_, acc3.z); \
    acc3.w = fmaf(__builtin_amdgcn_fmed3f(h3.CP + (HJ4).w, fmaf(e3.CP, ejw, -1.f), 0.f), wv_, acc3.w); }

// load the 4 hj rows of quad QQ into 4 NAMED float4s
#define LOADQ(QQ, B0, B1, B2, B3)                                             \
    B0 = *reinterpret_cast<const float4*>(hjq + (size_t)((QQ) * 4 + 0) * N_); \
    B1 = *reinterpret_cast<const float4*>(hjq + (size_t)((QQ) * 4 + 1) * N_); \
    B2 = *reinterpret_cast<const float4*>(hjq + (size_t)((QQ) * 4 + 2) * N_); \
    B3 = *reinterpret_cast<const float4*>(hjq + (size_t)((QQ) * 4 + 3) * N_);

#define COMPQ(QQ, B0, B1, B2, B3) {                                           \
    const int q_ = kq * 8 + (QQ);                                             \
    const float4 h0 = sU[q_][0], h1 = sU[q_][1], h2 = sU[q_][2], h3 = sU[q_][3]; \
    const float4 e0 = sU[q_][4], e1 = sU[q_][5], e2 = sU[q_][6], e3 = sU[q_][7]; \
    const float4 wq = sU[q_][8];                                              \
    SCORE_F(B0, x) SCORE_F(B1, y) SCORE_F(B2, z) SCORE_F(B3, w) }

// ---------------------------------------------------------------------------
// Kernel 2: FUSED score + row-MLP. 512 blocks x 512 thr; block owns 4 rows.
// Score phase: thread (kq=t>>7, u=t&127) owns j-quad x f-range (R15 layout).
// maxc/deg/zmask never leave LDS; the 32KB sAcc region is re-used (overlaid)
// by the MLP's sC/sP/sL1 after the reduction barrier.
// NO launch-bounds occupancy arg (R15 lesson: it caps VGPR -> scratch).
// ---------------------------------------------------------------------------
__global__ __launch_bounds__(512) void k_main(
    const float* __restrict__ Hi, const float* __restrict__ EHi,
    const float* __restrict__ HjT, const float* __restrict__ A,
    const float* __restrict__ dW2, const float* __restrict__ db2,
    const float* __restrict__ H, const float* __restrict__ csp,
    const float* __restrict__ rW1, const float* __restrict__ rb1,
    const float* __restrict__ rW2, const float* __restrict__ rb2,
    float* __restrict__ out, float* __restrict__ maskout) {
    __shared__ float4 sU[32][9];          // [quad][0..3]=hi rows,[4..7]=Ei,[8]=w
    __shared__ float  sBig[4 * 4 * N_];   // 32KB: score sAcc / mlp sC,sP,sL1
    __shared__ float  red_mx[8][4];
    __shared__ int    red_cnt[8][4];
    __shared__ unsigned long long sZb[8][4];
    __shared__ float  sMC[4], sDegF[4];
    const int t = threadIdx.x;
    const int lane = t & 63;
    const int w = t >> 6;                 // wave 0..7
    const int u  = t & 127;               // j-quad owner (score)
    const int kq = t >> 7;                // f-range owner (score) / K-quarter (mlp)
    const int f  = t & 127;               // mlp feature
    const int bi0 = blockIdx.x * 4;
    const int b = bi0 >> 9;

    // ---------------- score phase ----------------
    if (t < 288) {
        const int q  = t / 9;
        const int sl = t - q * 9;
        const float* src = (sl < 4) ? (Hi  + (size_t)(bi0 + sl)     * F_ + 4 * q)
                         : (sl < 8) ? (EHi + (size_t)(bi0 + sl - 4) * F_ + 4 * q)
                                    : (dW2 + 4 * q);
        sU[q][sl] = *reinterpret_cast<const float4*>(src);
    }
    float a_r[4];
    #pragma unroll
    for (int r = 0; r < 4; ++r) a_r[r] = A[(size_t)(bi0 + r) * N_ + t];

    const float* __restrict__ hjq = HjT + (size_t)b * F_ * N_
                                  + (size_t)(kq * 32) * N_ + 4 * u;
    float4 hA0, hA1, hA2, hA3, hB0, hB1, hB2, hB3;
    LOADQ(0, hA0, hA1, hA2, hA3)
    __syncthreads();

    float4 acc0 = {0.f,0.f,0.f,0.f}, acc1 = {0.f,0.f,0.f,0.f};
    float4 acc2 = {0.f,0.f,0.f,0.f}, acc3 = {0.f,0.f,0.f,0.f};

    LOADQ(1, hB0, hB1, hB2, hB3)
    COMPQ(0, hA0, hA1, hA2, hA3)
    LOADQ(2, hA0, hA1, hA2, hA3)
    COMPQ(1, hB0, hB1, hB2, hB3)
    LOADQ(3, hB0, hB1, hB2, hB3)
    COMPQ(2, hA0, hA1, hA2, hA3)
    LOADQ(4, hA0, hA1, hA2, hA3)
    COMPQ(3, hB0, hB1, hB2, hB3)
    LOADQ(5, hB0, hB1, hB2, hB3)
    COMPQ(4, hA0, hA1, hA2, hA3)
    LOADQ(6, hA0, hA1, hA2, hA3)
    COMPQ(5, hB0, hB1, hB2, hB3)
    LOADQ(7, hB0, hB1, hB2, hB3)
    COMPQ(6, hA0, hA1, hA2, hA3)
    COMPQ(7, hB0, hB1, hB2, hB3)

    // spill partial sums into sBig[(kq*4+r)*N_+4u .. +3]
    *reinterpret_cast<float4*>(&sBig[(kq * 4 + 0) * N_ + 4 * u]) = acc0;
    *reinterpret_cast<float4*>(&sBig[(kq * 4 + 1) * N_ + 4 * u]) = acc1;
    *reinterpret_cast<float4*>(&sBig[(kq * 4 + 2) * N_ + 4 * u]) = acc2;
    *reinterpret_cast<float4*>(&sBig[(kq * 4 + 3) * N_ + 4 * u]) = acc3;
    __syncthreads();

    // t = j layout: sum over kq, mask, ballot, wave-reduce
    #pragma unroll
    for (int r = 0; r < 4; ++r) {
        const float a = a_r[r];
        const float sum = sBig[(0 * 4 + r) * N_ + t] + sBig[(1 * 4 + r) * N_ + t]
                        + sBig[(2 * 4 + r) * N_ + t] + sBig[(3 * 4 + r) * N_ + t];
        float mx = (a > 0.1f) ? sum : -INFINITY;
        #pragma unroll
        for (int off = 1; off < 64; off <<= 1)
            mx = fmaxf(mx, __shfl_xor(mx, off));
        const unsigned long long pos = __ballot(a > 0.f);
        const unsigned long long zb  = __ballot(a <= 0.f);
        if (lane == 0) {
            red_mx[w][r]  = mx;
            red_cnt[w][r] = (int)__popcll(pos);
            sZb[w][r]     = zb;
        }
    }
    __syncthreads();
    if (t < 4) {
        float m = -INFINITY; int c = 0;
        #pragma unroll
        for (int ww = 0; ww < 8; ++ww) {
            m = fmaxf(m, red_mx[ww][t]);
            c += red_cnt[ww][t];
        }
        const float mc = (m > -INFINITY)
                       ? 1.f / (1.f + __expf(-(m + db2[0]))) : 0.f;
        sMC[t]   = mc;
        sDegF[t] = (float)c;
        maskout[bi0 + t] = (mc > 0.5f) ? 1.f : 0.f;
    }
    __syncthreads();   // sMC/sDegF visible; all sBig(score) reads complete

    // ---------------- mlp phase (overlays sBig) ----------------
    float* sC  = sBig;           // [4][260]
    float* sP  = sBig + 1040;    // [3][4][128]
    float* sL1 = sBig + 2576;    // [4][128]

    {   // stage H + assembled nf (thread's row = kq)
        const int row = bi0 + kq;
        sC[kq * 260 + f] = H[(size_t)row * F_ + f];
        float cs = 0.f;
        #pragma unroll
        for (int e = 0; e < 8; ++e)
            cs += csp[((size_t)b * 8 + e) * F_ + f];
        #pragma unroll
        for (int wv = 0; wv < 8; ++wv) {
            unsigned long long zb = sZb[wv][kq];
            while (zb) {                    // wave-uniform; empty in practice
                const int j = __ffsll(zb) - 1;
                zb &= zb - 1;
                cs -= H[((size_t)b * N_ + wv * 64 + j) * F_ + f];
            }
        }
        sC[kq * 260 + F_ + f] = cs / fmaxf(sDegF[kq], 1.f);
    }
    __syncthreads();

    // ---- layer 1 ----
    float macc[4];
    {
        const float bias = rb1[f];
        #pragma unroll
        for (int r = 0; r < 4; ++r) macc[r] = (kq == 0) ? bias : 0.f;
    }
    const int k0 = kq * 64;
    #pragma unroll 4
    for (int k = k0; k < k0 + 64; ++k) {
        const float wv = rW1[(size_t)k * F_ + f];
        #pragma unroll
        for (int r = 0; r < 4; ++r) macc[r] = fmaf(sC[r * 260 + k], wv, macc[r]);
    }
    if (kq == 3) {
        const float w256 = rW1[(size_t)256 * F_ + f];
        #pragma unroll
        for (int r = 0; r < 4; ++r) macc[r] = fmaf(sMC[r], w256, macc[r]);
    }
    if (kq > 0) {
        #pragma unroll
        for (int r = 0; r < 4; ++r) sP[((kq - 1) * 4 + r) * F_ + f] = macc[r];
    }
    __syncthreads();
    if (kq == 0) {
        #pragma unroll
        for (int r = 0; r < 4; ++r)
            sL1[r * F_ + f] = elu_f(macc[r] + sP[(0 * 4 + r) * F_ + f]
                                   + sP[(1 * 4 + r) * F_ + f]
                                   + sP[(2 * 4 + r) * F_ + f]);
    }
    __syncthreads();

    // ---- layer 2 ----
    float macc2[4];
    {
        const float bias2 = rb2[f];
        #pragma unroll
        for (int r = 0; r < 4; ++r) macc2[r] = (kq == 0) ? bias2 : 0.f;
    }
    const int m0k = kq * 32;
    #pragma unroll 4
    for (int k = m0k; k < m0k + 32; ++k) {
        const float wv = rW2[(size_t)k * F_ + f];
        #pragma unroll
        for (int r = 0; r < 4; ++r) macc2[r] = fmaf(sL1[r * F_ + k], wv, macc2[r]);
    }
    if (kq > 0) {
        #pragma unroll
        for (int r = 0; r < 4; ++r) sP[((kq - 1) * 4 + r) * F_ + f] = macc2[r];
    }
    __syncthreads();
    if (kq == 0) {
        #pragma unroll
        for (int r = 0; r < 4; ++r) {
            const int row = bi0 + r;
            const float res = macc2[r] + sP[(0 * 4 + r) * F_ + f]
                            + sP[(1 * 4 + r) * F_ + f]
                            + sP[(2 * 4 + r) * F_ + f];
            const bool upd = (sMC[r] > 0.5f) && (sDegF[r] > 0.f);
            out[(size_t)row * F_ + f] = upd ? res : sC[r * 260 + f];
        }
    }
}

// ---------------------------------------------------------------------------
extern "C" void kernel_launch(void* const* d_in, const int* in_sizes, int n_in,
                              void* d_out, int out_size, void* d_ws, size_t ws_size,
                              hipStream_t stream) {
    const float* H   = (const float*)d_in[0];
    const float* A   = (const float*)d_in[1];
    const float* dW1 = (const float*)d_in[2];
    const float* db1 = (const float*)d_in[3];
    const float* dW2 = (const float*)d_in[4];
    const float* db2 = (const float*)d_in[5];
    const float* rW1 = (const float*)d_in[6];
    const float* rb1 = (const float*)d_in[7];
    const float* rW2 = (const float*)d_in[8];
    const float* rb2 = (const float*)d_in[9];

    float* ws  = (float*)d_ws;
    float* Hi  = ws;                       // [BN][F]
    float* EHi = Hi  + BN_ * F_;           // [BN][F]
    float* HjT = EHi + BN_ * F_;           // [B][F][N]
    float* csp = HjT + BN_ * F_;           // [B][8][F]

    float* out      = (float*)d_out;       // [BN][F]
    float* mask_out = out + BN_ * F_;      // [BN]

    k_pre <<<NG_ + 32, 512, 0, stream>>>(H, dW1, db1, Hi, EHi, HjT, csp);
    k_main<<<NG_, 512, 0, stream>>>(Hi, EHi, HjT, A, dW2, db2,
                                    H, csp, rW1, rb1, rW2, rb2,
                                    out, mask_out);
}

// Round 17
// 41.657 us; speedup vs baseline: 1.0067x; 1.0067x over previous
//
#include <hip/hip_runtime.h>
#include <cmath>

#define B_ 4
#define N_ 512
#define F_ 128
#define BN_ (B_*N_)   // 2048
#define NG_ (BN_/4)   // 512 row-groups of 4

__device__ __forceinline__ float elu_f(float x) {
    return fmaxf(x, __expf(fminf(x, 0.f)) - 1.f);
}

// ---------------------------------------------------------------------------
// Kernel 1 (544 blocks x 512 thr):
//  blocks [0,512):   lin1 for 4 rows — Hi = H@dW1[:F]+db1, EHi = exp(Hi),
//                    HjT[b][f][n] = (H@dW1[F:])^T. K split across kq=t>>7.
//  blocks [512,544): colsum partials: csp[b][e][f] = sum of 64 H rows.
// ---------------------------------------------------------------------------
__global__ __launch_bounds__(512, 4) void k_pre(
    const float* __restrict__ H, const float* __restrict__ dW1,
    const float* __restrict__ db1,
    float* __restrict__ Hi, float* __restrict__ EHi, float* __restrict__ HjT,
    float* __restrict__ csp) {
    __shared__ float sH[4][F_];
    __shared__ float sPA[3][4][F_], sPB[3][4][F_];
    const int t = threadIdx.x;
    const int f = t & 127;
    const int kq = t >> 7;
    if (blockIdx.x < NG_) {
        // ---------------- lin1 ----------------
        const int row0 = blockIdx.x * 4;
        const int b  = row0 >> 9;
        const int n0 = row0 & 511;
        sH[kq][f] = H[(size_t)(row0 + kq) * F_ + f];
        __syncthreads();
        float accA[4] = {0.f,0.f,0.f,0.f}, accB[4] = {0.f,0.f,0.f,0.f};
        const int k0 = kq * 32;
        #pragma unroll 4
        for (int k = k0; k < k0 + 32; ++k) {
            const float wa = dW1[(size_t)k * F_ + f];
            const float wb = dW1[(size_t)(F_ + k) * F_ + f];
            #pragma unroll
            for (int r = 0; r < 4; ++r) {
                accA[r] = fmaf(sH[r][k], wa, accA[r]);
                accB[r] = fmaf(sH[r][k], wb, accB[r]);
            }
        }
        if (kq > 0) {
            #pragma unroll
            for (int r = 0; r < 4; ++r) {
                sPA[kq - 1][r][f] = accA[r];
                sPB[kq - 1][r][f] = accB[r];
            }
        }
        __syncthreads();
        if (kq == 0) {
            const float bias = db1[f];
            float bsum[4];
            #pragma unroll
            for (int r = 0; r < 4; ++r) {
                const float av = accA[r] + sPA[0][r][f] + sPA[1][r][f]
                               + sPA[2][r][f] + bias;
                Hi [(size_t)(row0 + r) * F_ + f] = av;
                EHi[(size_t)(row0 + r) * F_ + f] = __expf(av);
                bsum[r] = accB[r] + sPB[0][r][f] + sPB[1][r][f] + sPB[2][r][f];
            }
            float4 hv;
            hv.x = bsum[0]; hv.y = bsum[1]; hv.z = bsum[2]; hv.w = bsum[3];
            *reinterpret_cast<float4*>(HjT + ((size_t)b * F_ + f) * N_ + n0) = hv;
        }
    } else {
        // ---------------- colsum partial ----------------
        const int bx = blockIdx.x - NG_;   // 0..31
        const int b  = bx >> 3;
        const int e  = bx & 7;             // batch-eighth (64 rows)
        float s = 0.f;
        const float* hp = H + ((size_t)b * N_ + e * 64 + kq * 16) * F_ + f;
        #pragma unroll 4
        for (int jj = 0; jj < 16; ++jj) s += hp[(size_t)jj * F_];
        sH[kq][f] = s;
        __syncthreads();
        if (kq == 0)
            csp[((size_t)b * 8 + e) * F_ + f] =
                sH[0][f] + sH[1][f] + sH[2][f] + sH[3][f];
    }
}

// one f-slice: uniforms = component CP of (h0..h3, e0..e3, wq); 4 j's = HJ4.
#define SCORE_F(HJ4, CP) {                                                    \
    const float ejx = __expf((HJ4).x), ejy = __expf((HJ4).y),                 \
                ejz = __expf((HJ4).z), ejw = __expf((HJ4).w);                 \
    const float wv_ = wq.CP;                                                  \
    acc0.x = fmaf(__builtin_amdgcn_fmed3f(h0.CP + (HJ4).x, fmaf(e0.CP, ejx, -1.f), 0.f), wv_, acc0.x); \
    acc0.y = fmaf(__builtin_amdgcn_fmed3f(h0.CP + (HJ4).y, fmaf(e0.CP, ejy, -1.f), 0.f), wv_, acc0.y); \
    acc0.z = fmaf(__builtin_amdgcn_fmed3f(h0.CP + (HJ4).z, fmaf(e0.CP, ejz, -1.f), 0.f), wv_, acc0.z); \
    acc0.w = fmaf(__builtin_amdgcn_fmed3f(h0.CP + (HJ4).w, fmaf(e0.CP, ejw, -1.f), 0.f), wv_, acc0.w); \
    acc1.x = fmaf(__builtin_amdgcn_fmed3f(h1.CP + (HJ4).x, fmaf(e1.CP, ejx, -1.f), 0.f), wv_, acc1.x); \
    acc1.y = fmaf(__builtin_amdgcn_fmed3f(h1.CP + (HJ4).y, fmaf(e1.CP, ejy, -1.f), 0.f), wv_, acc1.y); \
    acc1.z = fmaf(__builtin_amdgcn_fmed3f(h1.CP + (HJ4).z, fmaf(e1.CP, ejz, -1.f), 0.f), wv_, acc1.z); \
    acc1.w = fmaf(__builtin_amdgcn_fmed3f(h1.CP + (HJ4).w, fmaf(e1.CP, ejw, -1.f), 0.f), wv_, acc1.w); \
    acc2.x = fmaf(__builtin_amdgcn_fmed3f(h2.CP + (HJ4).x, fmaf(e2.CP, ejx, -1.f), 0.f), wv_, acc2.x); \
    acc2.y = fmaf(__builtin_amdgcn_fmed3f(h2.CP + (HJ4).y, fmaf(e2.CP, ejy, -1.f), 0.f), wv_, acc2.y); \
    acc2.z = fmaf(__builtin_amdgcn_fmed3f(h2.CP + (HJ4).z, fmaf(e2.CP, ejz, -1.f), 0.f), wv_, acc2.z); \
    acc2.w = fmaf(__builtin_amdgcn_fmed3f(h2.CP + (HJ4).w, fmaf(e2.CP, ejw, -1.f), 0.f), wv_, acc2.w); \
    acc3.x = fmaf(__builtin_amdgcn_fmed3f(h3.CP + (HJ4).x, fmaf(e3.CP, ejx, -1.f), 0.f), wv_, acc3.x); \
    acc3.y = fmaf(__builtin_amdgcn_fmed3f(h3.CP + (HJ4).y, fmaf(e3.CP, ejy, -1.f), 0.f), wv_, acc3.y); \
    acc3.z = fmaf(__builtin_amdgcn_fmed3f(h3.CP + (HJ4).z, fmaf(e3.CP, ejz, -1.f), 0.f), wv_, acc3.z); \
    acc3.w = fmaf(__builtin_amdgcn_fmed3f(h3.CP + (HJ4).w, fmaf(e3.CP, ejw, -1.f), 0.f), wv_, acc3.w); }

// load the 4 hj rows of quad QQ into 4 NAMED float4s
#define LOADQ(QQ, B0, B1, B2, B3)                                             \
    B0 = *reinterpret_cast<const float4*>(hjq + (size_t)((QQ) * 4 + 0) * N_); \
    B1 = *reinterpret_cast<const float4*>(hjq + (size_t)((QQ) * 4 + 1) * N_); \
    B2 = *reinterpret_cast<const float4*>(hjq + (size_t)((QQ) * 4 + 2) * N_); \
    B3 = *reinterpret_cast<const float4*>(hjq + (size_t)((QQ) * 4 + 3) * N_);

#define COMPQ(QQ, B0, B1, B2, B3) {                                           \
    const int q_ = kq * 8 + (QQ);                                             \
    const float4 h0 = sU[q_][0], h1 = sU[q_][1], h2 = sU[q_][2], h3 = sU[q_][3]; \
    const float4 e0 = sU[q_][4], e1 = sU[q_][5], e2 = sU[q_][6], e3 = sU[q_][7]; \
    const float4 wq = sU[q_][8];                                              \
    SCORE_F(B0, x) SCORE_F(B1, y) SCORE_F(B2, z) SCORE_F(B3, w) }

// ---------------------------------------------------------------------------
// Kernel 2: FUSED score + row-MLP. 512 blocks x 512 thr; block owns 4 rows.
// mlp phase now reads sC/sL1 as float4 (96 b128 vs 384 b32 per wave) —
// the LDS-issue pipe was the suspected mlp bottleneck (R16: VALUBusy 37%).
// NO launch-bounds occupancy arg (R15 lesson: it caps VGPR -> scratch).
// ---------------------------------------------------------------------------
__global__ __launch_bounds__(512) void k_main(
    const float* __restrict__ Hi, const float* __restrict__ EHi,
    const float* __restrict__ HjT, const float* __restrict__ A,
    const float* __restrict__ dW2, const float* __restrict__ db2,
    const float* __restrict__ H, const float* __restrict__ csp,
    const float* __restrict__ rW1, const float* __restrict__ rb1,
    const float* __restrict__ rW2, const float* __restrict__ rb2,
    float* __restrict__ out, float* __restrict__ maskout) {
    __shared__ float4 sU[32][9];          // [quad][0..3]=hi rows,[4..7]=Ei,[8]=w
    __shared__ float  sBig[4 * 4 * N_];   // 32KB: score sAcc / mlp sC,sP,sL1
    __shared__ float  red_mx[8][4];
    __shared__ int    red_cnt[8][4];
    __shared__ unsigned long long sZb[8][4];
    __shared__ float  sMC[4], sDegF[4];
    const int t = threadIdx.x;
    const int lane = t & 63;
    const int w = t >> 6;                 // wave 0..7
    const int u  = t & 127;               // j-quad owner (score)
    const int kq = t >> 7;                // f-range owner (score) / K-quarter (mlp)
    const int f  = t & 127;               // mlp feature
    const int bi0 = blockIdx.x * 4;
    const int b = bi0 >> 9;

    // ---------------- score phase ----------------
    if (t < 288) {
        const int q  = t / 9;
        const int sl = t - q * 9;
        const float* src = (sl < 4) ? (Hi  + (size_t)(bi0 + sl)     * F_ + 4 * q)
                         : (sl < 8) ? (EHi + (size_t)(bi0 + sl - 4) * F_ + 4 * q)
                                    : (dW2 + 4 * q);
        sU[q][sl] = *reinterpret_cast<const float4*>(src);
    }
    float a_r[4];
    #pragma unroll
    for (int r = 0; r < 4; ++r) a_r[r] = A[(size_t)(bi0 + r) * N_ + t];

    const float* __restrict__ hjq = HjT + (size_t)b * F_ * N_
                                  + (size_t)(kq * 32) * N_ + 4 * u;
    float4 hA0, hA1, hA2, hA3, hB0, hB1, hB2, hB3;
    LOADQ(0, hA0, hA1, hA2, hA3)
    __syncthreads();

    float4 acc0 = {0.f,0.f,0.f,0.f}, acc1 = {0.f,0.f,0.f,0.f};
    float4 acc2 = {0.f,0.f,0.f,0.f}, acc3 = {0.f,0.f,0.f,0.f};

    LOADQ(1, hB0, hB1, hB2, hB3)
    COMPQ(0, hA0, hA1, hA2, hA3)
    LOADQ(2, hA0, hA1, hA2, hA3)
    COMPQ(1, hB0, hB1, hB2, hB3)
    LOADQ(3, hB0, hB1, hB2, hB3)
    COMPQ(2, hA0, hA1, hA2, hA3)
    LOADQ(4, hA0, hA1, hA2, hA3)
    COMPQ(3, hB0, hB1, hB2, hB3)
    LOADQ(5, hB0, hB1, hB2, hB3)
    COMPQ(4, hA0, hA1, hA2, hA3)
    LOADQ(6, hA0, hA1, hA2, hA3)
    COMPQ(5, hB0, hB1, hB2, hB3)
    LOADQ(7, hB0, hB1, hB2, hB3)
    COMPQ(6, hA0, hA1, hA2, hA3)
    COMPQ(7, hB0, hB1, hB2, hB3)

    // spill partial sums into sBig[(kq*4+r)*N_+4u .. +3]
    *reinterpret_cast<float4*>(&sBig[(kq * 4 + 0) * N_ + 4 * u]) = acc0;
    *reinterpret_cast<float4*>(&sBig[(kq * 4 + 1) * N_ + 4 * u]) = acc1;
    *reinterpret_cast<float4*>(&sBig[(kq * 4 + 2) * N_ + 4 * u]) = acc2;
    *reinterpret_cast<float4*>(&sBig[(kq * 4 + 3) * N_ + 4 * u]) = acc3;
    __syncthreads();

    // t = j layout: sum over kq, mask, ballot, wave-reduce
    #pragma unroll
    for (int r = 0; r < 4; ++r) {
        const float a = a_r[r];
        const float sum = sBig[(0 * 4 + r) * N_ + t] + sBig[(1 * 4 + r) * N_ + t]
                        + sBig[(2 * 4 + r) * N_ + t] + sBig[(3 * 4 + r) * N_ + t];
        float mx = (a > 0.1f) ? sum : -INFINITY;
        #pragma unroll
        for (int off = 1; off < 64; off <<= 1)
            mx = fmaxf(mx, __shfl_xor(mx, off));
        const unsigned long long pos = __ballot(a > 0.f);
        const unsigned long long zb  = __ballot(a <= 0.f);
        if (lane == 0) {
            red_mx[w][r]  = mx;
            red_cnt[w][r] = (int)__popcll(pos);
            sZb[w][r]     = zb;
        }
    }
    __syncthreads();
    if (t < 4) {
        float m = -INFINITY; int c = 0;
        #pragma unroll
        for (int ww = 0; ww < 8; ++ww) {
            m = fmaxf(m, red_mx[ww][t]);
            c += red_cnt[ww][t];
        }
        const float mc = (m > -INFINITY)
                       ? 1.f / (1.f + __expf(-(m + db2[0]))) : 0.f;
        sMC[t]   = mc;
        sDegF[t] = (float)c;
        maskout[bi0 + t] = (mc > 0.5f) ? 1.f : 0.f;
    }
    __syncthreads();   // sMC/sDegF visible; all sBig(score) reads complete

    // ---------------- mlp phase (overlays sBig) ----------------
    float* sC  = sBig;           // [4][260]
    float* sP  = sBig + 1040;    // [3][4][128]
    float* sL1 = sBig + 2576;    // [4][128]

    {   // stage H + assembled nf (thread's row = kq)
        const int row = bi0 + kq;
        sC[kq * 260 + f] = H[(size_t)row * F_ + f];
        float cs = 0.f;
        #pragma unroll
        for (int e = 0; e < 8; ++e)
            cs += csp[((size_t)b * 8 + e) * F_ + f];
        #pragma unroll
        for (int wv = 0; wv < 8; ++wv) {
            unsigned long long zb = sZb[wv][kq];
            while (zb) {                    // wave-uniform; empty in practice
                const int j = __ffsll(zb) - 1;
                zb &= zb - 1;
                cs -= H[((size_t)b * N_ + wv * 64 + j) * F_ + f];
            }
        }
        sC[kq * 260 + F_ + f] = cs / fmaxf(sDegF[kq], 1.f);
    }
    __syncthreads();

    // ---- layer 1: float4 LDS broadcast reads (k-quads) ----
    float macc[4];
    {
        const float bias = rb1[f];
        #pragma unroll
        for (int r = 0; r < 4; ++r) macc[r] = (kq == 0) ? bias : 0.f;
    }
    const int k0 = kq * 64;
    #pragma unroll 4
    for (int kk = 0; kk < 64; kk += 4) {
        const int k = k0 + kk;
        const float4 c0 = *reinterpret_cast<const float4*>(&sC[0 * 260 + k]);
        const float4 c1 = *reinterpret_cast<const float4*>(&sC[1 * 260 + k]);
        const float4 c2 = *reinterpret_cast<const float4*>(&sC[2 * 260 + k]);
        const float4 c3 = *reinterpret_cast<const float4*>(&sC[3 * 260 + k]);
        const float w0 = rW1[(size_t)(k + 0) * F_ + f];
        const float w1 = rW1[(size_t)(k + 1) * F_ + f];
        const float w2 = rW1[(size_t)(k + 2) * F_ + f];
        const float w3 = rW1[(size_t)(k + 3) * F_ + f];
        macc[0] = fmaf(c0.x, w0, macc[0]); macc[1] = fmaf(c1.x, w0, macc[1]);
        macc[2] = fmaf(c2.x, w0, macc[2]); macc[3] = fmaf(c3.x, w0, macc[3]);
        macc[0] = fmaf(c0.y, w1, macc[0]); macc[1] = fmaf(c1.y, w1, macc[1]);
        macc[2] = fmaf(c2.y, w1, macc[2]); macc[3] = fmaf(c3.y, w1, macc[3]);
        macc[0] = fmaf(c0.z, w2, macc[0]); macc[1] = fmaf(c1.z, w2, macc[1]);
        macc[2] = fmaf(c2.z, w2, macc[2]); macc[3] = fmaf(c3.z, w2, macc[3]);
        macc[0] = fmaf(c0.w, w3, macc[0]); macc[1] = fmaf(c1.w, w3, macc[1]);
        macc[2] = fmaf(c2.w, w3, macc[2]); macc[3] = fmaf(c3.w, w3, macc[3]);
    }
    if (kq == 3) {
        const float w256 = rW1[(size_t)256 * F_ + f];
        #pragma unroll
        for (int r = 0; r < 4; ++r) macc[r] = fmaf(sMC[r], w256, macc[r]);
    }
    if (kq > 0) {
        #pragma unroll
        for (int r = 0; r < 4; ++r) sP[((kq - 1) * 4 + r) * F_ + f] = macc[r];
    }
    __syncthreads();
    if (kq == 0) {
        #pragma unroll
        for (int r = 0; r < 4; ++r)
            sL1[r * F_ + f] = elu_f(macc[r] + sP[(0 * 4 + r) * F_ + f]
                                   + sP[(1 * 4 + r) * F_ + f]
                                   + sP[(2 * 4 + r) * F_ + f]);
    }
    __syncthreads();

    // ---- layer 2: float4 LDS broadcast reads ----
    float macc2[4];
    {
        const float bias2 = rb2[f];
        #pragma unroll
        for (int r = 0; r < 4; ++r) macc2[r] = (kq == 0) ? bias2 : 0.f;
    }
    const int m0k = kq * 32;
    #pragma unroll 4
    for (int kk = 0; kk < 32; kk += 4) {
        const int k = m0k + kk;
        const float4 l0 = *reinterpret_cast<const float4*>(&sL1[0 * F_ + k]);
        const float4 l1 = *reinterpret_cast<const float4*>(&sL1[1 * F_ + k]);
        const float4 l2 = *reinterpret_cast<const float4*>(&sL1[2 * F_ + k]);
        const float4 l3 = *reinterpret_cast<const float4*>(&sL1[3 * F_ + k]);
        const float w0 = rW2[(size_t)(k + 0) * F_ + f];
        const float w1 = rW2[(size_t)(k + 1) * F_ + f];
        const float w2 = rW2[(size_t)(k + 2) * F_ + f];
        const float w3 = rW2[(size_t)(k + 3) * F_ + f];
        macc2[0] = fmaf(l0.x, w0, macc2[0]); macc2[1] = fmaf(l1.x, w0, macc2[1]);
        macc2[2] = fmaf(l2.x, w0, macc2[2]); macc2[3] = fmaf(l3.x, w0, macc2[3]);
        macc2[0] = fmaf(l0.y, w1, macc2[0]); macc2[1] = fmaf(l1.y, w1, macc2[1]);
        macc2[2] = fmaf(l2.y, w1, macc2[2]); macc2[3] = fmaf(l3.y, w1, macc2[3]);
        macc2[0] = fmaf(l0.z, w2, macc2[0]); macc2[1] = fmaf(l1.z, w2, macc2[1]);
        macc2[2] = fmaf(l2.z, w2, macc2[2]); macc2[3] = fmaf(l3.z, w2, macc2[3]);
        macc2[0] = fmaf(l0.w, w3, macc2[0]); macc2[1] = fmaf(l1.w, w3, macc2[1]);
        macc2[2] = fmaf(l2.w, w3, macc2[2]); macc2[3] = fmaf(l3.w, w3, macc2[3]);
    }
    if (kq > 0) {
        #pragma unroll
        for (int r = 0; r < 4; ++r) sP[((kq - 1) * 4 + r) * F_ + f] = macc2[r];
    }
    __syncthreads();
    if (kq == 0) {
        #pragma unroll
        for (int r = 0; r < 4; ++r) {
            const int row = bi0 + r;
            const float res = macc2[r] + sP[(0 * 4 + r) * F_ + f]
                            + sP[(1 * 4 + r) * F_ + f]
                            + sP[(2 * 4 + r) * F_ + f];
            const bool upd = (sMC[r] > 0.5f) && (sDegF[r] > 0.f);
            out[(size_t)row * F_ + f] = upd ? res : sC[r * 260 + f];
        }
    }
}

// ---------------------------------------------------------------------------
extern "C" void kernel_launch(void* const* d_in, const int* in_sizes, int n_in,
                              void* d_out, int out_size, void* d_ws, size_t ws_size,
                              hipStream_t stream) {
    const float* H   = (const float*)d_in[0];
    const float* A   = (const float*)d_in[1];
    const float* dW1 = (const float*)d_in[2];
    const float* db1 = (const float*)d_in[3];
    const float* dW2 = (const float*)d_in[4];
    const float* db2 = (const float*)d_in[5];
    const float* rW1 = (const float*)d_in[6];
    const float* rb1 = (const float*)d_in[7];
    const float* rW2 = (const float*)d_in[8];
    const float* rb2 = (const float*)d_in[9];

    float* ws  = (float*)d_ws;
    float* Hi  = ws;                       // [BN][F]
    float* EHi = Hi  + BN_ * F_;           // [BN][F]
    float* HjT = EHi + BN_ * F_;           // [B][F][N]
    float* csp = HjT + BN_ * F_;           // [B][8][F]

    float* out      = (float*)d_out;       // [BN][F]
    float* mask_out = out + BN_ * F_;      // [BN]

    k_pre <<<NG_ + 32, 512, 0, stream>>>(H, dW1, db1, Hi, EHi, HjT, csp);
    k_main<<<NG_, 512, 0, stream>>>(Hi, EHi, HjT, A, dW2, db2,
                                    H, csp, rW1, rb1, rW2, rb2,
                                    out, mask_out);
}